// Round 1
// baseline (183.036 us; speedup 1.0000x reference)
//
#include <hip/hip_runtime.h>
#include <stdint.h>

typedef __attribute__((ext_vector_type(8))) short short8;
typedef __attribute__((ext_vector_type(4))) float f32x4;

#define NB 8
#define NC 1024
#define NHW 3136
#define ROWB (NHW*2)   // 6272 bytes per bf16 row

// fp32 -> bf16, round-to-nearest-even
__device__ inline unsigned short f2bf(float f){
  unsigned u = __builtin_bit_cast(unsigned int, f);
  u += 0x7fffu + ((u >> 16) & 1u);
  return (unsigned short)(u >> 16);
}

__device__ inline float sq4(float4 v){
  return fmaf(v.x,v.x, fmaf(v.y,v.y, fmaf(v.z,v.z, v.w*v.w)));
}

__device__ inline ushort4 bf4(float4 v, float s){
  ushort4 r;
  r.x = f2bf(v.x*s); r.y = f2bf(v.y*s);
  r.z = f2bf(v.z*s); r.w = f2bf(v.w*s);
  return r;
}

__device__ inline void load_lds16(const void* g, void* l){
  __builtin_amdgcn_global_load_lds(
      (const __attribute__((address_space(1))) unsigned int*)g,
      (__attribute__((address_space(3))) unsigned int*)l,
      16, 0, 0);
}

__global__ void k_init(float* acc){ acc[0] = 0.f; acc[1] = 0.f; }

// One block per row (3136 fp32). Load row into regs (float4), sum squares,
// block-reduce, scale, emit bf16. 16384 rows total (fm_s then fm_t).
__global__ __launch_bounds__(256) void k_norm(const float* __restrict__ s,
                                              const float* __restrict__ t,
                                              unsigned short* __restrict__ Sn,
                                              unsigned short* __restrict__ Tn){
  const int row = blockIdx.x;
  const float* src;
  unsigned short* dst;
  if (row < NB*NC) { src = s + (size_t)row*NHW;          dst = Sn + (size_t)row*NHW; }
  else             { int r = row - NB*NC;
                     src = t + (size_t)r*NHW;            dst = Tn + (size_t)r*NHW; }
  const int tid = threadIdx.x;
  const float4* sv = (const float4*)src;   // 784 float4 per row
  float4 v0 = sv[tid];
  float4 v1 = sv[tid+256];
  float4 v2 = sv[tid+512];
  float4 v3 = make_float4(0.f,0.f,0.f,0.f);
  if (tid < 16) v3 = sv[tid+768];
  float ssq = sq4(v0)+sq4(v1)+sq4(v2)+sq4(v3);
  #pragma unroll
  for (int off = 32; off; off >>= 1) ssq += __shfl_down(ssq, off);
  __shared__ float red[4];
  if ((tid & 63) == 0) red[tid>>6] = ssq;
  __syncthreads();
  const float tot = red[0]+red[1]+red[2]+red[3];
  const float inv = 1.0f / fmaxf(sqrtf(tot), 1e-12f);
  ushort4* dv = (ushort4*)dst;
  dv[tid]     = bf4(v0,inv);
  dv[tid+256] = bf4(v1,inv);
  dv[tid+512] = bf4(v2,inv);
  if (tid<16) dv[tid+768] = bf4(v3,inv);
}

// 128x128 tile, BK=64, 4 waves (2x2), 4x4 fragments of mfma_f32_16x16x32_bf16.
// A = [S_b; T_b] (2048 rows), B = S_b (1024 rows), per batch b. NT GEMM, both
// operands row-major with K (HW) contiguous. Output never stored: epilogue
// reduces sum(acc^2) and atomically accumulates into acc[0] (ss) / acc[1] (st).
__global__ __launch_bounds__(256,2) void k_gemm(const unsigned short* __restrict__ Sn,
                                                const unsigned short* __restrict__ Tn,
                                                float* __restrict__ accbuf){
  __shared__ unsigned short sA[128*64];
  __shared__ unsigned short sB[128*64];
  __shared__ float red[4];

  const int bid  = blockIdx.x;
  const int b    = bid >> 7;          // 128 tiles per batch
  const int tile = bid & 127;
  const int tm   = tile >> 3;         // 0..15 over 2048 A-rows
  const int tn   = tile & 7;          // 0..7  over 1024 B-rows
  const int tid  = threadIdx.x;
  const int lane = tid & 63;
  const int wave = tid >> 6;
  const int wr   = wave >> 1;
  const int wc   = wave & 1;

  const size_t bOff = (size_t)b * NC * NHW;
  const bool is_ss = (tm < 8);
  const unsigned short* Asrc = is_ss ? (Sn + bOff + (size_t)tm*128*NHW)
                                     : (Tn + bOff + (size_t)(tm-8)*128*NHW);
  const unsigned short* Bsrc = Sn + bOff + (size_t)tn*128*NHW;

  // Staging: LDS dest is linear (wave-uniform base + lane*16). XOR-swizzle is
  // applied on the GLOBAL source column so that LDS[row][cb] holds
  // A[row][(cb ^ ((row&7)<<4))/2].  row&7 == lane>>3 here.
  const int scol = ((lane & 7) << 4) ^ ((lane >> 3) << 4);
  const char* gA[4]; const char* gB[4];
  char* lA[4]; char* lB[4];
  #pragma unroll
  for (int i = 0; i < 4; i++){
    const int chunk = wave + 4*i;             // 1KB chunks, 16 per tile
    const int r = chunk*8 + (lane >> 3);      // local row 0..127
    gA[i] = (const char*)Asrc + (size_t)r*ROWB + scol;
    gB[i] = (const char*)Bsrc + (size_t)r*ROWB + scol;
    lA[i] = (char*)sA + chunk*1024;           // wave-uniform
    lB[i] = (char*)sB + chunk*1024;
  }

  // Fragment reads: A row r = wr*64+mi*16+(lane&15); r&7 == lane&7.
  const int la15 = lane & 15;
  const int swz  = (lane & 7) << 4;
  const int kp0  = ( ((lane >> 4) << 4)      ) ^ swz;
  const int kp1  = ( ((lane >> 4) << 4) + 64 ) ^ swz;
  const char* sAb = (const char*)sA + (wr*64 + la15)*128;
  const char* sBb = (const char*)sB + (wc*64 + la15)*128;

  f32x4 accv[4][4] = {};

  for (int k0 = 0; k0 < NHW/64; k0++){
    __syncthreads();                       // protect LDS WAR (drains lgkm)
    const int koff = k0*128;
    #pragma unroll
    for (int i = 0; i < 4; i++){
      load_lds16(gA[i]+koff, lA[i]);
      load_lds16(gB[i]+koff, lB[i]);
    }
    __syncthreads();                       // drains vmcnt before reads

    short8 af[4][2], bfr[4][2];
    #pragma unroll
    for (int mi = 0; mi < 4; mi++){
      af [mi][0] = *(const short8*)(sAb + mi*2048 + kp0);
      af [mi][1] = *(const short8*)(sAb + mi*2048 + kp1);
      bfr[mi][0] = *(const short8*)(sBb + mi*2048 + kp0);
      bfr[mi][1] = *(const short8*)(sBb + mi*2048 + kp1);
    }
    #pragma unroll
    for (int mi = 0; mi < 4; mi++)
      #pragma unroll
      for (int nj = 0; nj < 4; nj++){
        accv[mi][nj] = __builtin_amdgcn_mfma_f32_16x16x32_bf16(af[mi][0], bfr[nj][0], accv[mi][nj], 0,0,0);
        accv[mi][nj] = __builtin_amdgcn_mfma_f32_16x16x32_bf16(af[mi][1], bfr[nj][1], accv[mi][nj], 0,0,0);
      }
  }

  // Epilogue: sum of squares of this block's 128x128 tile (layout-free).
  float p = 0.f;
  #pragma unroll
  for (int mi = 0; mi < 4; mi++)
    #pragma unroll
    for (int nj = 0; nj < 4; nj++)
      #pragma unroll
      for (int e = 0; e < 4; e++)
        p = fmaf(accv[mi][nj][e], accv[mi][nj][e], p);
  #pragma unroll
  for (int off = 32; off; off >>= 1) p += __shfl_down(p, off);
  if (lane == 0) red[wave] = p;
  __syncthreads();
  if (tid == 0){
    atomicAdd(&accbuf[is_ss ? 0 : 1], red[0]+red[1]+red[2]+red[3]);
  }
}

__global__ void k_fin(const float* __restrict__ acc, float* __restrict__ out){
  out[0] = (acc[0] - 2.0f*acc[1]) * (1.0f / 8388608.0f);  // / (8*1024*1024)
}

extern "C" void kernel_launch(void* const* d_in, const int* in_sizes, int n_in,
                              void* d_out, int out_size, void* d_ws, size_t ws_size,
                              hipStream_t stream){
  const float* fs = (const float*)d_in[0];
  const float* ft = (const float*)d_in[1];
  float* out = (float*)d_out;
  float* accbuf = (float*)d_ws;
  unsigned short* Sn = (unsigned short*)((char*)d_ws + 256);
  unsigned short* Tn = Sn + (size_t)NB*NC*NHW;   // needs ~103 MB of ws total

  k_init<<<1, 1, 0, stream>>>(accbuf);
  k_norm<<<dim3(2*NB*NC), dim3(256), 0, stream>>>(fs, ft, Sn, Tn);
  k_gemm<<<dim3(NB*128), dim3(256), 0, stream>>>(Sn, Tn, accbuf);
  k_fin<<<1, 1, 0, stream>>>(accbuf, out);
}

// Round 2
// 128.228 us; speedup vs baseline: 1.4274x; 1.4274x over previous
//
#include <hip/hip_runtime.h>
#include <stdint.h>

typedef __attribute__((ext_vector_type(8))) short short8;
typedef __attribute__((ext_vector_type(4))) float f32x4;

#define NB 8
#define NC 1024
#define NHW 3136
#define ROWB (NHW*2)      // 6272 bytes per bf16 row
#define NKT 49            // K-tiles of 64

// fp32 -> bf16, round-to-nearest-even
__device__ inline unsigned short f2bf(float f){
  unsigned u = __builtin_bit_cast(unsigned int, f);
  u += 0x7fffu + ((u >> 16) & 1u);
  return (unsigned short)(u >> 16);
}
__device__ inline float sq4(float4 v){
  return fmaf(v.x,v.x, fmaf(v.y,v.y, fmaf(v.z,v.z, v.w*v.w)));
}
__device__ inline ushort4 bf4(float4 v, float s){
  ushort4 r;
  r.x = f2bf(v.x*s); r.y = f2bf(v.y*s);
  r.z = f2bf(v.z*s); r.w = f2bf(v.w*s);
  return r;
}
__device__ __forceinline__ void load_lds16(const void* g, void* l){
  __builtin_amdgcn_global_load_lds(
      (const __attribute__((address_space(1))) unsigned int*)g,
      (__attribute__((address_space(3))) unsigned int*)l,
      16, 0, 0);
}
__device__ __forceinline__ f32x4 MF(short8 a, short8 b, f32x4 c){
  return __builtin_amdgcn_mfma_f32_16x16x32_bf16(a, b, c, 0, 0, 0);
}
// 8 x ds_read_b128: fragments f[m][ks] at b0/b1 + m*2048
__device__ __forceinline__ void rd8(const char* b0, const char* b1, short8 f[4][2]){
  #pragma unroll
  for (int m = 0; m < 4; m++){
    f[m][0] = *(const short8*)(b0 + m*2048);
    f[m][1] = *(const short8*)(b1 + m*2048);
  }
}

__global__ void k_init(float* acc){ acc[0] = 0.f; acc[1] = 0.f; }

__global__ __launch_bounds__(256) void k_norm(const float* __restrict__ s,
                                              const float* __restrict__ t,
                                              unsigned short* __restrict__ Sn,
                                              unsigned short* __restrict__ Tn){
  const int row = blockIdx.x;
  const float* src;
  unsigned short* dst;
  if (row < NB*NC) { src = s + (size_t)row*NHW;          dst = Sn + (size_t)row*NHW; }
  else             { int r = row - NB*NC;
                     src = t + (size_t)r*NHW;            dst = Tn + (size_t)r*NHW; }
  const int tid = threadIdx.x;
  const float4* sv = (const float4*)src;   // 784 float4 per row
  float4 v0 = sv[tid];
  float4 v1 = sv[tid+256];
  float4 v2 = sv[tid+512];
  float4 v3 = make_float4(0.f,0.f,0.f,0.f);
  if (tid < 16) v3 = sv[tid+768];
  float ssq = sq4(v0)+sq4(v1)+sq4(v2)+sq4(v3);
  #pragma unroll
  for (int off = 32; off; off >>= 1) ssq += __shfl_down(ssq, off);
  __shared__ float red[4];
  if ((tid & 63) == 0) red[tid>>6] = ssq;
  __syncthreads();
  const float tot = red[0]+red[1]+red[2]+red[3];
  const float inv = 1.0f / fmaxf(sqrtf(tot), 1e-12f);
  ushort4* dv = (ushort4*)dst;
  dv[tid]     = bf4(v0,inv);
  dv[tid+256] = bf4(v1,inv);
  dv[tid+512] = bf4(v2,inv);
  if (tid<16) dv[tid+768] = bf4(v3,inv);
}

// ---------------- 256x256 8-phase GEMM with fused squared-sum reduction ----
// A = (st: T_b tile tm) or (ss: S_b tile tm); B = S_b tile tn; NT layout,
// K contiguous. ss computed on upper triangle only, off-diag weight 2.
// 8 waves as 2(M)x4(N); per-wave 128x64 output = acc[8][4] f32x4.
// LDS: buf d in {0,1}: A at d*65536, B at d*65536+32768 (row r: 128B,
// col-byte cb stored at cb ^ ((r&7)<<4) -- T2 swizzle, applied on the
// GLOBAL source for staging (rule #21) and on the ds_read address).

#define BAR   __builtin_amdgcn_s_barrier()
#define LGKM0 asm volatile("s_waitcnt lgkmcnt(0)" ::: "memory")
#define VM6   asm volatile("s_waitcnt vmcnt(6)" ::: "memory")
#define SB0   __builtin_amdgcn_sched_barrier(0)
#define PRIO1 __builtin_amdgcn_s_setprio(1)
#define PRIO0 __builtin_amdgcn_s_setprio(0)

// MAT: 0=A,1=B. Stages one 128-row half-tile (2 x global_load_lds / thread).
#define ISSUE(MAT, D, H, KT) do{ \
  const char* _g = ((MAT)? gB : gA) + (KT)*128 + (H)*(128*ROWB); \
  char* _d = ldsw + (D)*65536 + (MAT)*32768 + (H)*16384; \
  load_lds16(_g,           _d); \
  load_lds16(_g + 64*ROWB, _d + 8192); \
}while(0)

// one C-quadrant over K=64: 16 MFMA, static acc indices
#define MMQ(MH, NH) do{ \
  _Pragma("unroll") \
  for (int _m = 0; _m < 4; _m++){ \
    _Pragma("unroll") \
    for (int _n = 0; _n < 2; _n++){ \
      acc[(MH)*4+_m][(NH)*2+_n] = MF(af[_m][0], bf[(NH)*2+_n][0], acc[(MH)*4+_m][(NH)*2+_n]); \
      acc[(MH)*4+_m][(NH)*2+_n] = MF(af[_m][1], bf[(NH)*2+_n][1], acc[(MH)*4+_m][(NH)*2+_n]); \
    } \
  } \
}while(0)

__global__ __launch_bounds__(512,2) void k_gemm(const unsigned short* __restrict__ Sn,
                                                const unsigned short* __restrict__ Tn,
                                                float* __restrict__ accbuf){
  __shared__ char lds[131072];
  const int tid = threadIdx.x;
  const int l   = tid & 63;
  const int w   = tid >> 6;
  const int wr  = w >> 2;      // 0..1
  const int wc  = w & 3;       // 0..3

  const int b   = blockIdx.x & 7;    // batch -> XCD (208 = 8*26)
  const int idx = blockIdx.x >> 3;   // 0..25
  int tm, tn, which; float wgt;
  if (idx < 16){ which = 1; tm = idx >> 2; tn = idx & 3; wgt = 1.f; }
  else {
    int e = idx - 16; which = 0;
    if      (e < 4){ tm = 0; tn = e;   }
    else if (e < 7){ tm = 1; tn = e-3; }
    else if (e < 9){ tm = 2; tn = e-5; }
    else           { tm = 3; tn = 3;   }
    wgt = (tm == tn) ? 1.f : 2.f;
  }
  const size_t bOff = (size_t)b * NC * NHW;
  const unsigned short* Ab = (which ? Tn : Sn) + bOff + (size_t)tm * (256*NHW);
  const unsigned short* Bb = Sn               + bOff + (size_t)tn * (256*NHW);

  // staging: lane l covers row (8w + l>>3) of each 64-row issue group,
  // source col pre-swizzled so linear LDS dest holds the swizzled layout
  const int scol = ((l & 7) << 4) ^ ((l >> 3) << 4);
  const char* gA = (const char*)Ab + (8*w + (l >> 3))*ROWB + scol;
  const char* gB = (const char*)Bb + (8*w + (l >> 3))*ROWB + scol;
  char* ldsw = lds + w*1024;

  // fragment ds_read bases (swizzled); + D*65536, A: + mh*8192 + m*2048
  const int hi16 = (l >> 4) << 4;
  const int swz  = (l & 7) << 4;
  const char* a0 = lds +         (wr*128 + (l & 15))*128 + ((hi16     ) ^ swz);
  const char* a1 = lds +         (wr*128 + (l & 15))*128 + ((hi16 + 64) ^ swz);
  const char* b0 = lds + 32768 + (wc*64  + (l & 15))*128 + ((hi16     ) ^ swz);
  const char* b1 = lds + 32768 + (wc*64  + (l & 15))*128 + ((hi16 + 64) ^ swz);

  short8 af[4][2], bf[4][2];
  f32x4 acc[8][4];
  #pragma unroll
  for (int i = 0; i < 8; i++)
    #pragma unroll
    for (int j = 0; j < 4; j++)
      acc[i][j] = (f32x4){0.f, 0.f, 0.f, 0.f};

  // Prologue: t0 fully (B,B,A,A) + t1 (B,B,A); t1.Ah1 issued at ph0.
  ISSUE(1,0,0,0); ISSUE(1,0,1,0); ISSUE(0,0,0,0); ISSUE(0,0,1,0);
  ISSUE(1,1,0,1); ISSUE(1,1,1,1); ISSUE(0,1,0,1);
  VM6; BAR;   // oldest 8 issues (= all of t0) landed

  for (int i = 0; i < 24; i++){
    const int t1 = 2*i + 1;
    const int t2 = 2*i + 2;
    int t3 = 2*i + 3; if (t3 > 48) t3 = 48;   // clamp keeps vmcnt uniform

    // ---- tile t0 = 2i (buf0) ----
    // ph0: read A-mh0 + all B; issue t1.Ah1
    rd8(a0, a1, af); rd8(b0, b1, bf);
    ISSUE(0,1,1,t1);
    BAR; LGKM0; SB0; PRIO1; MMQ(0,0); PRIO0; BAR;
    // ph1: issue t2.Bh0
    ISSUE(1,0,0,t2);
    BAR; PRIO1; MMQ(0,1); PRIO0; BAR;
    // ph2: read A-mh1; issue t2.Bh1
    rd8(a0 + 8192, a1 + 8192, af);
    ISSUE(1,0,1,t2);
    BAR; LGKM0; SB0; PRIO1; MMQ(1,0); PRIO0; BAR;
    // ph3: issue t2.Ah0; counted drain for tile t1
    ISSUE(0,0,0,t2);
    BAR; PRIO1; MMQ(1,1); PRIO0; VM6; BAR;

    // ---- tile t1 = 2i+1 (buf1) ----
    // ph4
    rd8(a0 + 65536, a1 + 65536, af); rd8(b0 + 65536, b1 + 65536, bf);
    ISSUE(0,0,1,t2);
    BAR; LGKM0; SB0; PRIO1; MMQ(0,0); PRIO0; BAR;
    // ph5
    ISSUE(1,1,0,t3);
    BAR; PRIO1; MMQ(0,1); PRIO0; BAR;
    // ph6
    rd8(a0 + 65536 + 8192, a1 + 65536 + 8192, af);
    ISSUE(1,1,1,t3);
    BAR; LGKM0; SB0; PRIO1; MMQ(1,0); PRIO0; BAR;
    // ph7: counted drain for tile t2
    ISSUE(0,1,0,t3);
    BAR; PRIO1; MMQ(1,1); PRIO0; VM6; BAR;
  }

  // Epilogue: tile 48 (buf0); landed per loop-end VM6 (junk issues are the
  // 3 newest half-tiles). No barriers needed: no LDS writes conflict (junk
  // DMA targets buf1 only).
  rd8(a0, a1, af); rd8(b0, b1, bf);
  MMQ(0,0); MMQ(0,1);
  rd8(a0 + 8192, a1 + 8192, af);
  MMQ(1,0); MMQ(1,1);

  // Fused reduction: sum of squares of the 256x256 tile (layout-free).
  float p = 0.f;
  #pragma unroll
  for (int i = 0; i < 8; i++)
    #pragma unroll
    for (int j = 0; j < 4; j++)
      #pragma unroll
      for (int e = 0; e < 4; e++)
        p = fmaf(acc[i][j][e], acc[i][j][e], p);
  #pragma unroll
  for (int off = 32; off; off >>= 1) p += __shfl_down(p, off);
  __syncthreads();
  float* red = (float*)lds;
  if (l == 0) red[w] = p;
  __syncthreads();
  if (tid == 0){
    float s = red[0]+red[1]+red[2]+red[3]+red[4]+red[5]+red[6]+red[7];
    atomicAdd(&accbuf[which], wgt * s);
  }
}

__global__ void k_fin(const float* __restrict__ acc, float* __restrict__ out){
  out[0] = (acc[0] - 2.0f*acc[1]) * (1.0f / 8388608.0f);  // / (8*1024*1024)
}

extern "C" void kernel_launch(void* const* d_in, const int* in_sizes, int n_in,
                              void* d_out, int out_size, void* d_ws, size_t ws_size,
                              hipStream_t stream){
  const float* fs = (const float*)d_in[0];
  const float* ft = (const float*)d_in[1];
  float* out = (float*)d_out;
  float* accbuf = (float*)d_ws;
  unsigned short* Sn = (unsigned short*)((char*)d_ws + 256);
  unsigned short* Tn = Sn + (size_t)NB*NC*NHW;   // ~103 MB of ws total

  k_init<<<1, 1, 0, stream>>>(accbuf);
  k_norm<<<dim3(2*NB*NC), dim3(256), 0, stream>>>(fs, ft, Sn, Tn);
  k_gemm<<<dim3(208), dim3(512), 0, stream>>>(Sn, Tn, accbuf);
  k_fin<<<1, 1, 0, stream>>>(accbuf, out);
}

// Round 3
// 124.914 us; speedup vs baseline: 1.4653x; 1.0265x over previous
//
#include <hip/hip_runtime.h>
#include <stdint.h>

typedef __attribute__((ext_vector_type(8))) short short8;
typedef __attribute__((ext_vector_type(4))) float f32x4;

#define NB 8
#define NC 1024
#define NHW 3136
#define ROWB (NHW*2)      // 6272 bytes per bf16 row

// fp32 -> bf16, round-to-nearest-even
__device__ inline unsigned short f2bf(float f){
  unsigned u = __builtin_bit_cast(unsigned int, f);
  u += 0x7fffu + ((u >> 16) & 1u);
  return (unsigned short)(u >> 16);
}
__device__ inline float sq4(float4 v){
  return fmaf(v.x,v.x, fmaf(v.y,v.y, fmaf(v.z,v.z, v.w*v.w)));
}
__device__ inline ushort4 bf4(float4 v, float s){
  ushort4 r;
  r.x = f2bf(v.x*s); r.y = f2bf(v.y*s);
  r.z = f2bf(v.z*s); r.w = f2bf(v.w*s);
  return r;
}
__device__ __forceinline__ void load_lds16(const void* g, void* l){
  __builtin_amdgcn_global_load_lds(
      (const __attribute__((address_space(1))) unsigned int*)g,
      (__attribute__((address_space(3))) unsigned int*)l,
      16, 0, 0);
}
__device__ __forceinline__ f32x4 MF(short8 a, short8 b, f32x4 c){
  return __builtin_amdgcn_mfma_f32_16x16x32_bf16(a, b, c, 0, 0, 0);
}
// 8 x ds_read_b128 (A-fragments for one MH half)
__device__ __forceinline__ void rd8(const char* b0, const char* b1, short8 f[4][2]){
  #pragma unroll
  for (int m = 0; m < 4; m++){
    f[m][0] = *(const short8*)(b0 + m*2048);
    f[m][1] = *(const short8*)(b1 + m*2048);
  }
}
// 4 x ds_read_b128 (two B n-fragments)
__device__ __forceinline__ void rdB2(const char* b0, const char* b1, short8 f[2][2]){
  f[0][0] = *(const short8*)(b0);
  f[0][1] = *(const short8*)(b1);
  f[1][0] = *(const short8*)(b0 + 2048);
  f[1][1] = *(const short8*)(b1 + 2048);
}

// One block per row (3136 fp32). Block 0 also zeroes the accumulators
// (deterministic each call; gemm runs after in stream order).
__global__ __launch_bounds__(256) void k_norm(const float* __restrict__ s,
                                              const float* __restrict__ t,
                                              unsigned short* __restrict__ Sn,
                                              unsigned short* __restrict__ Tn,
                                              float* __restrict__ accbuf){
  const int row = blockIdx.x;
  const int tid = threadIdx.x;
  if (row == 0 && tid == 0){ accbuf[0] = 0.f; accbuf[1] = 0.f; }
  const float* src;
  unsigned short* dst;
  if (row < NB*NC) { src = s + (size_t)row*NHW;          dst = Sn + (size_t)row*NHW; }
  else             { int r = row - NB*NC;
                     src = t + (size_t)r*NHW;            dst = Tn + (size_t)r*NHW; }
  const float4* sv = (const float4*)src;   // 784 float4 per row
  float4 v0 = sv[tid];
  float4 v1 = sv[tid+256];
  float4 v2 = sv[tid+512];
  float4 v3 = make_float4(0.f,0.f,0.f,0.f);
  if (tid < 16) v3 = sv[tid+768];
  float ssq = sq4(v0)+sq4(v1)+sq4(v2)+sq4(v3);
  #pragma unroll
  for (int off = 32; off; off >>= 1) ssq += __shfl_down(ssq, off);
  __shared__ float red[4];
  if ((tid & 63) == 0) red[tid>>6] = ssq;
  __syncthreads();
  const float tot = red[0]+red[1]+red[2]+red[3];
  const float inv = 1.0f / fmaxf(sqrtf(tot), 1e-12f);
  ushort4* dv = (ushort4*)dst;
  dv[tid]     = bf4(v0,inv);
  dv[tid+256] = bf4(v1,inv);
  dv[tid+512] = bf4(v2,inv);
  if (tid<16) dv[tid+768] = bf4(v3,inv);
}

// ---------------- 256x256 8-phase GEMM with fused squared-sum reduction ----
// A = (st: T_b tile tm) or (ss: S_b tile tm); B = S_b tile tn; NT layout,
// K contiguous. ss computed on upper triangle only, off-diag weight 2.
// 8 waves as 2(M)x4(N); per-wave 128x64 output = acc[8][4] f32x4.
// LDS: buf d in {0,1}: A at d*65536, B at d*65536+32768 (row r: 128B,
// col-byte cb stored at cb ^ ((r&7)<<4) -- T2 swizzle, applied on the
// GLOBAL source for staging (rule #21) and on the ds_read address).
// Phase read balance: 12/4/8/0 ds_read_b128 (m201 template), lgkmcnt(8)
// throttle in the 12-read phases.

#define BAR   __builtin_amdgcn_s_barrier()
#define LGKM0 asm volatile("s_waitcnt lgkmcnt(0)" ::: "memory")
#define LGKM8 asm volatile("s_waitcnt lgkmcnt(8)" ::: "memory")
#define VM6   asm volatile("s_waitcnt vmcnt(6)" ::: "memory")
#define SB0   __builtin_amdgcn_sched_barrier(0)
#define PRIO1 __builtin_amdgcn_s_setprio(1)
#define PRIO0 __builtin_amdgcn_s_setprio(0)

// MAT: 0=A,1=B. Stages one 128-row half-tile (2 x global_load_lds / thread).
#define ISSUE(MAT, D, H, KT) do{ \
  const char* _g = ((MAT)? gB : gA) + (KT)*128 + (H)*(128*ROWB); \
  char* _d = ldsw + (D)*65536 + (MAT)*32768 + (H)*16384; \
  load_lds16(_g,           _d); \
  load_lds16(_g + 64*ROWB, _d + 8192); \
}while(0)

// one C-quadrant over K=64: 16 MFMA, static acc indices
#define MMQ(MH, NH) do{ \
  _Pragma("unroll") \
  for (int _m = 0; _m < 4; _m++){ \
    _Pragma("unroll") \
    for (int _n = 0; _n < 2; _n++){ \
      acc[(MH)*4+_m][(NH)*2+_n] = MF(af[_m][0], bf[(NH)*2+_n][0], acc[(MH)*4+_m][(NH)*2+_n]); \
      acc[(MH)*4+_m][(NH)*2+_n] = MF(af[_m][1], bf[(NH)*2+_n][1], acc[(MH)*4+_m][(NH)*2+_n]); \
    } \
  } \
}while(0)

__global__ __launch_bounds__(512,2) void k_gemm(const unsigned short* __restrict__ Sn,
                                                const unsigned short* __restrict__ Tn,
                                                float* __restrict__ accbuf){
  __shared__ char lds[131072];
  const int tid = threadIdx.x;
  const int l   = tid & 63;
  const int w   = tid >> 6;
  const int wr  = w >> 2;      // 0..1
  const int wc  = w & 3;       // 0..3

  const int b   = blockIdx.x & 7;    // batch -> XCD (208 = 8*26)
  const int idx = blockIdx.x >> 3;   // 0..25
  int tm, tn, which; float wgt;
  if (idx < 16){ which = 1; tm = idx >> 2; tn = idx & 3; wgt = 1.f; }
  else {
    int e = idx - 16; which = 0;
    if      (e < 4){ tm = 0; tn = e;   }
    else if (e < 7){ tm = 1; tn = e-3; }
    else if (e < 9){ tm = 2; tn = e-5; }
    else           { tm = 3; tn = 3;   }
    wgt = (tm == tn) ? 1.f : 2.f;
  }
  const size_t bOff = (size_t)b * NC * NHW;
  const unsigned short* Ab = (which ? Tn : Sn) + bOff + (size_t)tm * (256*NHW);
  const unsigned short* Bb = Sn               + bOff + (size_t)tn * (256*NHW);

  // staging: lane l covers row (8w + l>>3) of each 64-row issue group,
  // source col pre-swizzled so linear LDS dest holds the swizzled layout
  const int scol = ((l & 7) << 4) ^ ((l >> 3) << 4);
  const char* gA = (const char*)Ab + (8*w + (l >> 3))*ROWB + scol;
  const char* gB = (const char*)Bb + (8*w + (l >> 3))*ROWB + scol;
  char* ldsw = lds + w*1024;

  // fragment ds_read bases (swizzled); + D*65536, A: + mh*8192 + m*2048
  const int hi16 = (l >> 4) << 4;
  const int swz  = (l & 7) << 4;
  const char* a0 = lds +         (wr*128 + (l & 15))*128 + ((hi16     ) ^ swz);
  const char* a1 = lds +         (wr*128 + (l & 15))*128 + ((hi16 + 64) ^ swz);
  const char* b0 = lds + 32768 + (wc*64  + (l & 15))*128 + ((hi16     ) ^ swz);
  const char* b1 = lds + 32768 + (wc*64  + (l & 15))*128 + ((hi16 + 64) ^ swz);

  short8 af[4][2], bf[4][2];
  f32x4 acc[8][4];
  #pragma unroll
  for (int i = 0; i < 8; i++)
    #pragma unroll
    for (int j = 0; j < 4; j++)
      acc[i][j] = (f32x4){0.f, 0.f, 0.f, 0.f};

  // Prologue: t0 fully (B,B,A,A) + t1 (B,B,A); t1.Ah1 issued at ph0.
  ISSUE(1,0,0,0); ISSUE(1,0,1,0); ISSUE(0,0,0,0); ISSUE(0,0,1,0);
  ISSUE(1,1,0,1); ISSUE(1,1,1,1); ISSUE(0,1,0,1);
  VM6; BAR;   // oldest 8 issues (= all of t0) landed

  for (int i = 0; i < 24; i++){
    const int t1 = 2*i + 1;
    const int t2 = 2*i + 2;
    int t3 = 2*i + 3; if (t3 > 48) t3 = 48;   // clamp keeps vmcnt uniform

    // ---- tile t0 = 2i (buf0) ----
    // ph0 (12 reads): af-mh0 + bf01; issue t1.Ah1
    rd8(a0, a1, af); rdB2(b0, b1, &bf[0]);
    ISSUE(0,1,1,t1);
    LGKM8; BAR; LGKM0; SB0; PRIO1; MMQ(0,0); PRIO0; BAR;
    // ph1 (4 reads): bf23  (B reads of buf0 finish here)
    rdB2(b0 + 4096, b1 + 4096, &bf[2]);
    BAR; LGKM0; SB0; PRIO1; MMQ(0,1); PRIO0; BAR;
    // ph2 (8 reads): af-mh1; issue t2.Bh0+Bh1 (safe: after ph1's barrier)
    rd8(a0 + 8192, a1 + 8192, af);
    ISSUE(1,0,0,t2); ISSUE(1,0,1,t2);
    BAR; LGKM0; SB0; PRIO1; MMQ(1,0); PRIO0; BAR;
    // ph3: issue t2.Ah0; counted drain for tile t1
    ISSUE(0,0,0,t2);
    BAR; PRIO1; MMQ(1,1); PRIO0; VM6; BAR;

    // ---- tile t1 = 2i+1 (buf1) ----
    // ph4 (12 reads)
    rd8(a0 + 65536, a1 + 65536, af); rdB2(b0 + 65536, b1 + 65536, &bf[0]);
    ISSUE(0,0,1,t2);
    LGKM8; BAR; LGKM0; SB0; PRIO1; MMQ(0,0); PRIO0; BAR;
    // ph5 (4 reads)
    rdB2(b0 + 65536 + 4096, b1 + 65536 + 4096, &bf[2]);
    BAR; LGKM0; SB0; PRIO1; MMQ(0,1); PRIO0; BAR;
    // ph6 (8 reads)
    rd8(a0 + 65536 + 8192, a1 + 65536 + 8192, af);
    ISSUE(1,1,0,t3); ISSUE(1,1,1,t3);
    BAR; LGKM0; SB0; PRIO1; MMQ(1,0); PRIO0; BAR;
    // ph7: counted drain for tile t2
    ISSUE(0,1,0,t3);
    BAR; PRIO1; MMQ(1,1); PRIO0; VM6; BAR;
  }

  // Epilogue: tile 48 (buf0); fully landed (ph7's VM6 + closing barrier --
  // junk t3 issues are the 3 newest half-tiles and target buf1 only).
  rd8(a0, a1, af); rdB2(b0, b1, &bf[0]); rdB2(b0 + 4096, b1 + 4096, &bf[2]);
  MMQ(0,0); MMQ(0,1);
  rd8(a0 + 8192, a1 + 8192, af);
  MMQ(1,0); MMQ(1,1);

  // Fused reduction: sum of squares of the 256x256 tile (layout-free).
  float p = 0.f;
  #pragma unroll
  for (int i = 0; i < 8; i++)
    #pragma unroll
    for (int j = 0; j < 4; j++)
      #pragma unroll
      for (int e = 0; e < 4; e++)
        p = fmaf(acc[i][j][e], acc[i][j][e], p);
  #pragma unroll
  for (int off = 32; off; off >>= 1) p += __shfl_down(p, off);
  __syncthreads();
  float* red = (float*)lds;
  if (l == 0) red[w] = p;
  __syncthreads();
  if (tid == 0){
    float s = red[0]+red[1]+red[2]+red[3]+red[4]+red[5]+red[6]+red[7];
    atomicAdd(&accbuf[which], wgt * s);
  }
}

__global__ void k_fin(const float* __restrict__ acc, float* __restrict__ out){
  out[0] = (acc[0] - 2.0f*acc[1]) * (1.0f / 8388608.0f);  // / (8*1024*1024)
}

extern "C" void kernel_launch(void* const* d_in, const int* in_sizes, int n_in,
                              void* d_out, int out_size, void* d_ws, size_t ws_size,
                              hipStream_t stream){
  const float* fs = (const float*)d_in[0];
  const float* ft = (const float*)d_in[1];
  float* out = (float*)d_out;
  float* accbuf = (float*)d_ws;
  unsigned short* Sn = (unsigned short*)((char*)d_ws + 256);
  unsigned short* Tn = Sn + (size_t)NB*NC*NHW;   // ~103 MB of ws total

  k_norm<<<dim3(2*NB*NC), dim3(256), 0, stream>>>(fs, ft, Sn, Tn, accbuf);
  k_gemm<<<dim3(208), dim3(512), 0, stream>>>(Sn, Tn, accbuf);
  k_fin<<<1, 1, 0, stream>>>(accbuf, out);
}

// Round 4
// 85.264 us; speedup vs baseline: 2.1467x; 1.4650x over previous
//
#include <hip/hip_runtime.h>
#include <stdint.h>

typedef __attribute__((ext_vector_type(4)))  int   i32x4;
typedef __attribute__((ext_vector_type(8)))  int   i32x8;
typedef __attribute__((ext_vector_type(16))) float f32x16;

#define NB 8
#define NC 1024
#define NHW 3136
#define ROWB8 3200        // fp8 row stride: 3136 data + 64 zero pad = 25*128
#define NKT 25            // K-tiles of 128 fp8 elements (128 B)

__device__ inline float sq4(float4 v){
  return fmaf(v.x,v.x, fmaf(v.y,v.y, fmaf(v.z,v.z, v.w*v.w)));
}

__device__ __forceinline__ void load_lds16(const void* g, void* l){
  __builtin_amdgcn_global_load_lds(
      (const __attribute__((address_space(1))) unsigned int*)g,
      (__attribute__((address_space(3))) unsigned int*)l,
      16, 0, 0);
}

// MX-scaled fp8 MFMA, both formats e4m3 (fmt=0), all block scales = 2^0
// (0x7F in every byte -> whichever byte opsel picks, scale is 1.0).
__device__ __forceinline__ f32x16 MFS(i32x8 a, i32x8 b, f32x16 c){
  return __builtin_amdgcn_mfma_scale_f32_32x32x64_f8f6f4(
      a, b, c, 0, 0, 0, 0x7F7F7F7F, 0, 0x7F7F7F7F);
}

__device__ __forceinline__ i32x8 rdfrag(const char* base, int cLo, int cHi){
  i32x4 lo = *(const i32x4*)(base + cLo);
  i32x4 hi = *(const i32x4*)(base + cHi);
  return __builtin_shufflevector(lo, hi, 0,1,2,3,4,5,6,7);
}

// One block per row (3136 fp32): sum squares, normalize, pre-scale by 32,
// emit OCP e4m3 fp8 + 64 B zero pad. Thread t<196 owns 16 contiguous elems.
// Block 0 thread 0 zeroes the global accumulators (stream-ordered before gemm).
__global__ __launch_bounds__(256) void k_norm(const float* __restrict__ s,
                                              const float* __restrict__ t,
                                              char* __restrict__ Sn,
                                              char* __restrict__ Tn,
                                              float* __restrict__ accbuf){
  const int row = blockIdx.x;
  const int tid = threadIdx.x;
  if (row == 0 && tid == 0){ accbuf[0] = 0.f; accbuf[1] = 0.f; }
  const float* src; char* dst;
  if (row < NB*NC) { src = s + (size_t)row*NHW;            dst = Sn + (size_t)row*ROWB8; }
  else             { int r = row - NB*NC;
                     src = t + (size_t)r*NHW;              dst = Tn + (size_t)r*ROWB8; }
  const float4* sv = (const float4*)src;   // 784 float4 per row; 196*4 = 784
  float4 v[4] = {};
  float ssq = 0.f;
  if (tid < 196){
    #pragma unroll
    for (int j = 0; j < 4; j++){ v[j] = sv[4*tid + j]; ssq += sq4(v[j]); }
  }
  #pragma unroll
  for (int off = 32; off; off >>= 1) ssq += __shfl_down(ssq, off);
  __shared__ float red[4];
  if ((tid & 63) == 0) red[tid>>6] = ssq;
  __syncthreads();
  const float inv = 32.0f / fmaxf(sqrtf(red[0]+red[1]+red[2]+red[3]), 1e-12f);
  if (tid < 196){
    int w[4];
    #pragma unroll
    for (int j = 0; j < 4; j++){
      int pk = __builtin_amdgcn_cvt_pk_fp8_f32(v[j].x*inv, v[j].y*inv, 0,  0);
      pk     = __builtin_amdgcn_cvt_pk_fp8_f32(v[j].z*inv, v[j].w*inv, pk, 1);
      w[j] = pk;
    }
    *(int4*)(dst + tid*16) = make_int4(w[0], w[1], w[2], w[3]);
  } else if (tid < 200){
    *(int4*)(dst + 3136 + (tid-196)*16) = make_int4(0,0,0,0);  // K pad
  }
}

// ---------------- 256x256 8-phase MX-fp8 GEMM, fused squared-sum -----------
// Same verified schedule as the bf16 kernel (ISSUE cadence, swizzle, vmcnt
// accounting, 12/4/8/0 ds_read phases) -- only dtype/fragments changed.
// K-tile = 128 fp8 = 128 B per row (identical staging footprint).
// 8 waves 2(M)x4(N); per-wave 128x64 out = 4 m-frags x 2 n-frags of 32x32,
// acc[8] f32x16. Dots come out scaled by 2^10 (both inputs pre-scaled 2^5);
// squared sums by 2^20, divided out in k_fin.

#define BAR   __builtin_amdgcn_s_barrier()
#define LGKM0 asm volatile("s_waitcnt lgkmcnt(0)" ::: "memory")
#define LGKM8 asm volatile("s_waitcnt lgkmcnt(8)" ::: "memory")
#define VM6   asm volatile("s_waitcnt vmcnt(6)" ::: "memory")
#define SB0   __builtin_amdgcn_sched_barrier(0)
#define PRIO1 __builtin_amdgcn_s_setprio(1)
#define PRIO0 __builtin_amdgcn_s_setprio(0)

// MAT: 0=A,1=B. Stages one 128-row half-tile (2 x global_load_lds / thread).
#define ISSUE(MAT, D, H, KT) do{ \
  const char* _g = ((MAT)? gB : gA) + (KT)*128 + (H)*(128*ROWB8); \
  char* _d = ldsw + (D)*65536 + (MAT)*32768 + (H)*16384; \
  load_lds16(_g,              _d); \
  load_lds16(_g + 64*ROWB8,   _d + 8192); \
}while(0)

// A-fragments for half MH of buf D: af[m][ks], 8 x ds_read_b128
#define RDA(D, MH) do{ \
  const char* _a = aRow + (D) + (MH)*8192; \
  af[0][0] = rdfrag(_a,        c00, c01); \
  af[0][1] = rdfrag(_a,        c10, c11); \
  af[1][0] = rdfrag(_a + 4096, c00, c01); \
  af[1][1] = rdfrag(_a + 4096, c10, c11); \
}while(0)

// B-fragment NH of buf D: bf[NH][ks], 4 x ds_read_b128
#define RDB(D, NH) do{ \
  const char* _b = bRow + (D) + (NH)*4096; \
  bf[NH][0] = rdfrag(_b, c00, c01); \
  bf[NH][1] = rdfrag(_b, c10, c11); \
}while(0)

// One C-quadrant (MH half of M, NH n-frag) over K=128: 4 scaled MFMA,
// chains interleaved for ILP. acc index compile-time constant.
#define MMQ(MH, NH) do{ \
  acc[((MH)*2+0)*2+(NH)] = MFS(af[0][0], bf[NH][0], acc[((MH)*2+0)*2+(NH)]); \
  acc[((MH)*2+1)*2+(NH)] = MFS(af[1][0], bf[NH][0], acc[((MH)*2+1)*2+(NH)]); \
  acc[((MH)*2+0)*2+(NH)] = MFS(af[0][1], bf[NH][1], acc[((MH)*2+0)*2+(NH)]); \
  acc[((MH)*2+1)*2+(NH)] = MFS(af[1][1], bf[NH][1], acc[((MH)*2+1)*2+(NH)]); \
}while(0)

__global__ __launch_bounds__(512,2) void k_gemm(const char* __restrict__ Sn,
                                                const char* __restrict__ Tn,
                                                float* __restrict__ accbuf){
  __shared__ char lds[131072];
  const int tid = threadIdx.x;
  const int l   = tid & 63;
  const int w   = tid >> 6;
  const int wr  = w >> 2;      // 0..1
  const int wc  = w & 3;       // 0..3

  const int b   = blockIdx.x & 7;    // batch -> XCD (208 = 8*26)
  const int idx = blockIdx.x >> 3;   // 0..25
  int tm, tn, which; float wgt;
  if (idx < 16){ which = 1; tm = idx >> 2; tn = idx & 3; wgt = 1.f; }
  else {
    int e = idx - 16; which = 0;
    if      (e < 4){ tm = 0; tn = e;   }
    else if (e < 7){ tm = 1; tn = e-3; }
    else if (e < 9){ tm = 2; tn = e-5; }
    else           { tm = 3; tn = 3;   }
    wgt = (tm == tn) ? 1.f : 2.f;
  }
  const char* Ab = (which ? Tn : Sn) + (size_t)b*(NC*ROWB8) + (size_t)tm*(256*ROWB8);
  const char* Bb = Sn                + (size_t)b*(NC*ROWB8) + (size_t)tn*(256*ROWB8);

  // staging: lane l covers row (8w + l>>3) of each 64-row issue group;
  // source col pre-swizzled so the linear LDS dest holds the swizzled layout
  const int scol = ((l & 7) << 4) ^ ((l >> 3) << 4);
  const char* gA = Ab + (8*w + (l >> 3))*ROWB8 + scol;
  const char* gB = Bb + (8*w + (l >> 3))*ROWB8 + scol;
  char* ldsw = lds + w*1024;

  // fragment addressing: logical row r = (frag base) + (l&31), r&7 == l&7;
  // lane k-chunk = 32*(l>>5) bytes, split in two swizzled 16B slots.
  const int swz = (l & 7) << 4;
  const int cg  = 32*(l >> 5);
  const int c00 = ( cg           ) ^ swz;
  const int c01 = ( cg | 16      ) ^ swz;
  const int c10 = ( cg | 64      ) ^ swz;
  const int c11 = ( cg | 64 | 16 ) ^ swz;
  const char* aRow = lds +         (wr*128 + (l & 31))*128;  // + D + mfrag*4096
  const char* bRow = lds + 32768 + (wc*64  + (l & 31))*128;  // + D + nfrag*4096

  i32x8 af[2][2], bf[2][2];
  f32x16 acc[8];
  #pragma unroll
  for (int i = 0; i < 8; i++) acc[i] = (f32x16){};

  // Prologue: t0 fully (B,B,A,A) + t1 (B,B,A); t1.Ah1 issued at ph0.
  ISSUE(1,0,0,0); ISSUE(1,0,1,0); ISSUE(0,0,0,0); ISSUE(0,0,1,0);
  ISSUE(1,1,0,1); ISSUE(1,1,1,1); ISSUE(0,1,0,1);
  VM6; BAR;   // oldest 8 loads (= all of t0) landed

  for (int i = 0; i < 12; i++){
    const int t1 = 2*i + 1;
    const int t2 = 2*i + 2;
    int t3 = 2*i + 3; if (t3 > 24) t3 = 24;   // clamp keeps vmcnt uniform

    // ---- tile t0 = 2i (buf0) ----
    // ph0 (12 reads): A-mh0 + B-n0; issue t1.Ah1
    RDA(0,0); RDB(0,0);
    ISSUE(0,1,1,t1);
    LGKM8; BAR; LGKM0; SB0; PRIO1; MMQ(0,0); PRIO0; BAR;
    // ph1 (4 reads): B-n1
    RDB(0,1);
    BAR; LGKM0; SB0; PRIO1; MMQ(0,1); PRIO0; BAR;
    // ph2 (8 reads): A-mh1; issue t2.Bh0+Bh1
    RDA(0,1);
    ISSUE(1,0,0,t2); ISSUE(1,0,1,t2);
    BAR; LGKM0; SB0; PRIO1; MMQ(1,0); PRIO0; BAR;
    // ph3: issue t2.Ah0; counted drain for tile t1
    ISSUE(0,0,0,t2);
    BAR; PRIO1; MMQ(1,1); PRIO0; VM6; BAR;

    // ---- tile t1 = 2i+1 (buf1) ----
    // ph4 (12 reads)
    RDA(65536,0); RDB(65536,0);
    ISSUE(0,0,1,t2);
    LGKM8; BAR; LGKM0; SB0; PRIO1; MMQ(0,0); PRIO0; BAR;
    // ph5 (4 reads)
    RDB(65536,1);
    BAR; LGKM0; SB0; PRIO1; MMQ(0,1); PRIO0; BAR;
    // ph6 (8 reads)
    RDA(65536,1);
    ISSUE(1,1,0,t3); ISSUE(1,1,1,t3);
    BAR; LGKM0; SB0; PRIO1; MMQ(1,0); PRIO0; BAR;
    // ph7: counted drain for tile t2
    ISSUE(0,1,0,t3);
    BAR; PRIO1; MMQ(1,1); PRIO0; VM6; BAR;
  }

  // Epilogue: tile 24 (buf0), fully landed by final VM6+BAR (junk t3 issues
  // are the 3 newest half-tiles and target buf1 only). Deps order the reads.
  RDA(0,0); RDB(0,0); RDB(0,1);
  MMQ(0,0); MMQ(0,1);
  RDA(0,1);
  MMQ(1,0); MMQ(1,1);

  // Fused reduction: sum of squares of the 256x256 tile (layout-free;
  // invariant to any consistent fragment permutation).
  float p = 0.f;
  #pragma unroll
  for (int f = 0; f < 8; f++)
    #pragma unroll
    for (int e = 0; e < 16; e++)
      p = fmaf(acc[f][e], acc[f][e], p);
  #pragma unroll
  for (int off = 32; off; off >>= 1) p += __shfl_down(p, off);
  __syncthreads();
  float* red = (float*)lds;
  if (l == 0) red[w] = p;
  __syncthreads();
  if (tid == 0){
    float sum = red[0]+red[1]+red[2]+red[3]+red[4]+red[5]+red[6]+red[7];
    atomicAdd(&accbuf[which], wgt * sum);
  }
}

__global__ void k_fin(const float* __restrict__ acc, float* __restrict__ out){
  // / (8*1024*1024) and / 2^20 (both operands pre-scaled by 2^5)
  out[0] = (acc[0] - 2.0f*acc[1]) * 1.1368683772161603e-13f;   // 2^-43
}

extern "C" void kernel_launch(void* const* d_in, const int* in_sizes, int n_in,
                              void* d_out, int out_size, void* d_ws, size_t ws_size,
                              hipStream_t stream){
  const float* fs = (const float*)d_in[0];
  const float* ft = (const float*)d_in[1];
  float* out = (float*)d_out;
  float* accbuf = (float*)d_ws;
  char* Sn = (char*)d_ws + 256;
  char* Tn = Sn + (size_t)NB*NC*ROWB8;   // 2 x 26.2 MB of ws

  k_norm<<<dim3(2*NB*NC), dim3(256), 0, stream>>>(fs, ft, Sn, Tn, accbuf);
  k_gemm<<<dim3(208), dim3(512), 0, stream>>>(Sn, Tn, accbuf);
  k_fin<<<1, 1, 0, stream>>>(accbuf, out);
}